// Round 5
// baseline (2587.317 us; speedup 1.0000x reference)
//
#include <hip/hip_runtime.h>
#include <hip/hip_bf16.h>
#include <stdint.h>

#define BDIM 512

constexpr int Bb   = 256;            // batch
constexpr int Tt   = 512;            // timesteps
constexpr int Hh   = 512;            // hidden
constexpr int NPOS = 128, NACT = 64, INPD = 192;
constexpr int GBLK = 16;             // blocks per group
constexpr int RR   = 16;             // batch rows per group
constexpr int HHd  = 32;             // h dims per block
constexpr int KITH = Hh / 32;        // 16 h-part MFMA K-iters
constexpr int KITX = INPD / 32;      // 6  x-part MFMA K-iters
constexpr int KIT  = KITH + KITX;    // 22
constexpr int HPAD = Hh + 8;         // 520 shorts per h_s row
constexpr int GPAD = 132;            // gates row stride (fp32)

typedef __attribute__((ext_vector_type(8))) short short8;
typedef __attribute__((ext_vector_type(4))) float f32x4;
typedef __attribute__((ext_vector_type(4))) unsigned int u32x4;

__device__ __forceinline__ float bf2f(unsigned short u) {
  union { unsigned int i; float f; } v; v.i = ((unsigned int)u) << 16; return v.f;
}
__device__ __forceinline__ unsigned short f2bf(float f) {
  __hip_bfloat16 h = __float2bfloat16(f);
  return *reinterpret_cast<unsigned short*>(&h);
}
__device__ __forceinline__ float sigm(float x) { return 1.0f / (1.0f + __expf(-x)); }
__device__ __forceinline__ float tanh_fast(float x) {
  return 1.0f - 2.0f / (1.0f + __expf(2.0f * x));
}

// ---- fast ops: sc0 (L1-bypass, served by the XCD-shared L2) ----
__device__ __forceinline__ u32x4 load_l2_16(const void* p) {
  u32x4 r;
  asm volatile("global_load_dwordx4 %0, %1, off sc0" : "=v"(r) : "v"(p) : "memory");
  return r;
}
__device__ __forceinline__ unsigned int load_l2_4(const void* p) {
  unsigned int r;
  asm volatile("global_load_dword %0, %1, off sc0" : "=v"(r) : "v"(p) : "memory");
  return r;
}
__device__ __forceinline__ void store_l2_4(void* p, unsigned int v) {
  asm volatile("global_store_dword %0, %1, off sc0" :: "v"(p), "v"(v) : "memory");
}
// ---- device-scope ops: sc0 sc1 (bypass L1+L2, coherent at L3) — proven r2/r3 ----
__device__ __forceinline__ u32x4 load_dev16(const void* p) {
  u32x4 r;
  asm volatile("global_load_dwordx4 %0, %1, off sc0 sc1" : "=v"(r) : "v"(p) : "memory");
  return r;
}
__device__ __forceinline__ unsigned int load_dev4(const void* p) {
  unsigned int r;
  asm volatile("global_load_dword %0, %1, off sc0 sc1" : "=v"(r) : "v"(p) : "memory");
  return r;
}
__device__ __forceinline__ void store_dev4(void* p, unsigned int v) {
  asm volatile("global_store_dword %0, %1, off sc0 sc1" :: "v"(p), "v"(v) : "memory");
}
__device__ __forceinline__ void store_dev2(void* p, unsigned short v) {
  unsigned int w = v;
  asm volatile("global_store_short %0, %1, off sc0 sc1" :: "v"(p), "v"(w) : "memory");
}
__device__ __forceinline__ void waitvm0() {
  asm volatile("s_waitcnt vmcnt(0)" ::: "memory");
}

__global__ void __launch_bounds__(BDIM, 2)
lstm_kernel(const float* __restrict__ obs, const float* __restrict__ actn,
            const float* __restrict__ h0, const float* __restrict__ c0,
            const float* __restrict__ W_ih, const float* __restrict__ W_hh,
            const float* __restrict__ b_ih, const float* __restrict__ b_hh,
            const float* __restrict__ W_out, const float* __restrict__ b_out,
            float* __restrict__ out, unsigned short* __restrict__ hbuf,
            unsigned int* __restrict__ flags, unsigned int* __restrict__ rankcnt,
            unsigned int* __restrict__ grpbad, unsigned int* __restrict__ tok)
{
  __shared__ __align__(16) unsigned short h_s[RR * HPAD]; // [16][520] bf16
  __shared__ float gates_s[RR * GPAD];                    // [16][132] fp32
  __shared__ float c_s[RR * HHd];                         // [16][32] fp32 cell state
  __shared__ float wout_s[Hh];
  __shared__ float bias_s[4 * HHd];
  __shared__ int rank_sh;
  __shared__ int okA_sh, okB_sh, dev_sh;

  const int tid  = threadIdx.x;
  const int wv   = tid >> 6, lane = tid & 63;
  const int cl   = lane & 15, qd = lane >> 4;

  // ---- placement-derived grouping (heuristic; verified below) ----
  unsigned int xcc;
  asm volatile("s_getreg_b32 %0, hwreg(HW_REG_XCC_ID)" : "=s"(xcc));
  xcc &= 7u;
  if (tid == 0)
    rank_sh = (int)__hip_atomic_fetch_add(rankcnt + (size_t)xcc * 32, 1u,
                                          __ATOMIC_RELAXED, __HIP_MEMORY_SCOPE_AGENT);
  __syncthreads();
  const int rank = rank_sh;                      // arrival rank on this XCD
  const int g    = ((int)xcc * 2 + (rank >> 4)) & 15;  // group 0..15
  const int jb   = rank & 15;                          // slice 0..15

  unsigned short* hb0 = hbuf;
  unsigned short* hb1 = hbuf + (size_t)Bb * Hh;
  const size_t slotbase = (size_t)(g * GBLK + jb) * (RR * HHd);
  const size_t grpbase  = (size_t)g * GBLK * (RR * HHd);
  unsigned int* myflag = flags + (size_t)(g * GBLK + jb) * 32;     // 128B spacing
  const unsigned int* pollflag = flags + (size_t)(g * GBLK + (lane & 15)) * 32;
  unsigned int* mytok = tok + (size_t)(g * GBLK + jb) * 32;
  const unsigned int TOKA = 0xA5000000u | (unsigned)(g << 8) | (unsigned)jb;
  const unsigned int TOKB = 0x5A000000u | (unsigned)(g << 8) | (unsigned)jb;

  auto pollv = [&](unsigned int tgt, bool dv, int valve) {
    if (tid < 64) {
      int spins = 0;
      for (;;) {
        const unsigned int v = dv ? load_dev4(pollflag) : load_l2_4(pollflag);
        waitvm0();
        if (__all((int)(v >= tgt))) break;
        if (++spins > valve) break;              // wrong-not-hung safety valve
      }
    }
    __syncthreads();
  };
  auto verify_read = [&](unsigned int expbase) -> void {
    // wave 0, lanes 0..15 read the group's tokens with the FAST ops
    if (tid < 64) {
      int good = 1;
      if (lane < 16) {
        const unsigned int v = load_l2_4(tok + (size_t)(g * GBLK + lane) * 32);
        waitvm0();
        good = (v == (expbase | (unsigned)(g << 8) | (unsigned)lane)) ? 1 : 0;
      }
      const int allg = __all(good);
      if (lane == 0) { if (expbase == 0xA5000000u) okA_sh = allg; else okB_sh = allg; }
    }
  };

  // ---- phase 1: token A (fast store) + h0 (device store) ----
  if (tid == 0) store_l2_4(mytok, TOKA);
  {
    const int m = tid >> 5, r = tid & 31;
    const size_t gi = (size_t)(g * RR + m) * Hh + jb * HHd + r;
    c_s[tid] = c0[gi];
    store_dev2(hb0 + slotbase + tid, f2bf(h0[gi]));
  }
  waitvm0();
  __syncthreads();
  if (tid == 0) store_dev4(myflag, 1u);
  pollv(1u, true, 2000000);
  verify_read(0xA5000000u);                 // round A
  __syncthreads();
  if (tid == 0) store_dev4(myflag, 2u);     // "A reads done"
  pollv(2u, true, 2000000);
  if (tid == 0) {                           // round B: overwrite same line
    store_l2_4(mytok, TOKB);
    waitvm0();
    store_dev4(myflag, 3u);
  }
  pollv(3u, true, 2000000);
  verify_read(0x5A000000u);                 // round B (stale-detecting)
  __syncthreads();
  if (tid == 0) {
    if (!(okA_sh && okB_sh)) atomicOr(grpbad + (size_t)g * 32, 1u);  // device scope
    waitvm0();
    store_dev4(myflag, 4u);
  }
  pollv(4u, true, 2000000);
  if (tid == 0) {
    const unsigned int gb = load_dev4(grpbad + (size_t)g * 32);
    waitvm0();
    dev_sh = (gb != 0);
  }
  __syncthreads();
  const bool dev = (dev_sh != 0);           // block-uniform scope selector

  // ---- W slice -> register-resident bf16 MFMA B-fragments ----
  short8 wfrag[KIT];
  {
    const int L = wv * 16 + cl, q = L >> 5, r = L & 31;
    const int R = q * Hh + jb * HHd + r;
    const float* whh = W_hh + (size_t)R * Hh;
    const float* wih = W_ih + (size_t)R * INPD;
    #pragma unroll
    for (int kk = 0; kk < KIT; ++kk) {
      const int k0 = kk * 32 + qd * 8;
      short8 s;
      #pragma unroll
      for (int e = 0; e < 8; ++e) {
        const int k = k0 + e;
        const float f = (k < Hh) ? whh[k] : wih[k - Hh];
        s[e] = (short)f2bf(f);
      }
      wfrag[kk] = s;
    }
  }
  if (tid < 128) {
    const int q = tid >> 5, r = tid & 31;
    bias_s[tid] = b_ih[q * Hh + jb * HHd + r] + b_hh[q * Hh + jb * HHd + r];
  }
  wout_s[tid] = W_out[tid];
  const float bout = b_out[0];

  auto xacc_compute = [&](int t) -> f32x4 {
    f32x4 a;
    { const float bv = bias_s[wv * 16 + cl]; a = (f32x4){bv, bv, bv, bv}; }
    const int b = g * RR + cl;
    const float* orow = obs  + ((size_t)b * Tt + t) * NPOS;
    const float* arow = actn + ((size_t)b * Tt + t) * NACT;
    #pragma unroll
    for (int j = 0; j < KITX; ++j) {
      const int k0 = j * 32 + qd * 8;
      const float* src = (k0 < NPOS) ? (orow + k0) : (arow + (k0 - NPOS));
      const float4 v0 = *(const float4*)src;
      const float4 v1 = *(const float4*)(src + 4);
      short8 s;
      s[0] = (short)f2bf(v0.x); s[1] = (short)f2bf(v0.y);
      s[2] = (short)f2bf(v0.z); s[3] = (short)f2bf(v0.w);
      s[4] = (short)f2bf(v1.x); s[5] = (short)f2bf(v1.y);
      s[6] = (short)f2bf(v1.z); s[7] = (short)f2bf(v1.w);
      a = __builtin_amdgcn_mfma_f32_16x16x32_bf16(s, wfrag[KITH + j], a, 0, 0, 0);
    }
    return a;
  };

  f32x4 xacc = xacc_compute(0);

  for (int t = 0; t < Tt; ++t) {
    const unsigned short* hsrc = (t & 1) ? hb1 : hb0;  // h_{t-1}
    unsigned short* hdst       = (t & 1) ? hb0 : hb1;  // h_t

    // 1. load group's h (16 KB) at the verified scope -> LDS
    u32x4 hv0, hv1;
    if (dev) {
      hv0 = load_dev16(hsrc + grpbase + (size_t)tid * 8);
      hv1 = load_dev16(hsrc + grpbase + (size_t)(tid + 512) * 8);
    } else {
      hv0 = load_l2_16(hsrc + grpbase + (size_t)tid * 8);
      hv1 = load_l2_16(hsrc + grpbase + (size_t)(tid + 512) * 8);
    }
    waitvm0();
    {
      const int i0 = tid, i1 = tid + 512;
      *(u32x4*)&h_s[((i0 & 63) >> 2) * HPAD + ((i0 >> 6) << 5) + ((i0 & 3) << 3)] = hv0;
      *(u32x4*)&h_s[((i1 & 63) >> 2) * HPAD + ((i1 >> 6) << 5) + ((i1 & 3) << 3)] = hv1;
    }
    __syncthreads();

    // 2. h-part MFMA on carried x-part accumulator
    f32x4 acc = xacc;
    const unsigned short* ar = &h_s[cl * HPAD + qd * 8];
    #pragma unroll
    for (int kk = 0; kk < KITH; ++kk)
      acc = __builtin_amdgcn_mfma_f32_16x16x32_bf16(*(const short8*)(ar + kk * 32),
                                                    wfrag[kk], acc, 0, 0, 0);
    #pragma unroll
    for (int rg = 0; rg < 4; ++rg)
      gates_s[(qd * 4 + rg) * GPAD + wv * 16 + cl] = acc[rg];
    __syncthreads();

    // 3. LSTM elementwise; h_t published at the verified scope
    {
      const int m = tid >> 5, r = tid & 31;
      const float gi = gates_s[m * GPAD + r];
      const float gf = gates_s[m * GPAD + HHd + r];
      const float gg = gates_s[m * GPAD + 2 * HHd + r];
      const float go = gates_s[m * GPAD + 3 * HHd + r];
      const float cp = c_s[tid];
      const float iv = sigm(gi), fv = sigm(gf);
      const float gv = tanh_fast(gg), ov = sigm(go);
      const float cn = fv * cp + iv * gv;
      const float hn = ov * tanh_fast(cn);
      c_s[tid] = cn;
      const unsigned int hb = (unsigned int)f2bf(hn);
      const unsigned int hb2 = (unsigned int)__shfl_down((int)hb, 1, 64);
      if ((tid & 1) == 0) {
        if (dev) store_dev4(hdst + slotbase + tid, hb | (hb2 << 16));
        else     store_l2_4(hdst + slotbase + tid, hb | (hb2 << 16));
      }
    }
    waitvm0();
    __syncthreads();
    if (tid == 0) {
      if (dev) store_dev4(myflag, (unsigned int)(t + 5));
      else     store_l2_4(myflag, (unsigned int)(t + 5));
    }

    // 4. barrier window: out[t-1] from h_s, x-part for t+1
    if (jb == 0 && t > 0 && tid < 128) {
      const int m = tid >> 3, l8 = tid & 7;
      const unsigned short* hr = &h_s[m * HPAD + l8 * 64];
      const float* wr = &wout_s[l8 * 64];
      float sum = 0.f;
      #pragma unroll 8
      for (int e = 0; e < 64; ++e) sum += bf2f(hr[e]) * wr[e];
      sum += __shfl_down(sum, 4, 64);
      sum += __shfl_down(sum, 2, 64);
      sum += __shfl_down(sum, 1, 64);
      if (l8 == 0) out[(size_t)(g * RR + m) * Tt + (t - 1)] = sum + bout;
    }
    if (t + 1 < Tt) xacc = xacc_compute(t + 1);

    // 5. wait for whole group's h_t
    pollv((unsigned int)(t + 5), dev, 200000);
  }

  // final column: h_{T-1} in hb0 (T even)
  if (jb == 0 && tid < 128) {
    const int m = tid >> 3, l8 = tid & 7;
    float sum = 0.f;
    #pragma unroll
    for (int it = 0; it < 8; ++it) {
      const int d = l8 * 64 + it * 8;
      const void* p = hb0 + grpbase + (size_t)(d >> 5) * (RR * HHd) + m * HHd + (d & 31);
      const u32x4 v = dev ? load_dev16(p) : load_l2_16(p);
      waitvm0();
      #pragma unroll
      for (int j2 = 0; j2 < 4; ++j2) {
        sum += bf2f((unsigned short)(v[j2] & 0xffffu)) * wout_s[d + j2 * 2];
        sum += bf2f((unsigned short)(v[j2] >> 16))     * wout_s[d + j2 * 2 + 1];
      }
    }
    sum += __shfl_down(sum, 4, 64);
    sum += __shfl_down(sum, 2, 64);
    sum += __shfl_down(sum, 1, 64);
    if (l8 == 0) out[(size_t)(g * RR + m) * Tt + (Tt - 1)] = sum + bout;
  }
}

extern "C" void kernel_launch(void* const* d_in, const int* in_sizes, int n_in,
                              void* d_out, int out_size, void* d_ws, size_t ws_size,
                              hipStream_t stream) {
  const float* obs   = (const float*)d_in[0];
  const float* actn  = (const float*)d_in[1];
  const float* h0    = (const float*)d_in[2];
  const float* c0    = (const float*)d_in[3];
  const float* W_ih  = (const float*)d_in[4];
  const float* W_hh  = (const float*)d_in[5];
  const float* b_ih  = (const float*)d_in[6];
  const float* b_hh  = (const float*)d_in[7];
  const float* W_out = (const float*)d_in[8];
  const float* b_out = (const float*)d_in[9];
  float* out = (float*)d_out;

  // ws layout: hbuf 512K | flags 32K | rankcnt 1K | grpbad 2K | tok 32K
  unsigned short* hbuf = (unsigned short*)d_ws;
  char* p = (char*)d_ws + (size_t)2 * Bb * Hh * sizeof(unsigned short);
  unsigned int* flags   = (unsigned int*)p;
  unsigned int* rankcnt = (unsigned int*)(p + 32768);
  unsigned int* grpbad  = (unsigned int*)(p + 32768 + 1024);
  unsigned int* tokp    = (unsigned int*)(p + 32768 + 1024 + 2048);

  hipMemsetAsync(p, 0, 32768 + 1024 + 2048 + 32768, stream);

  // LDS pad -> 1 block/CU -> all 256 blocks co-resident (spin-safe)
  hipFuncSetAttribute((const void*)lstm_kernel,
                      hipFuncAttributeMaxDynamicSharedMemorySize, 53248);
  hipLaunchKernelGGL(lstm_kernel, dim3(256), dim3(BDIM), 53248, stream,
                     obs, actn, h0, c0, W_ih, W_hh, b_ih, b_hh, W_out, b_out,
                     out, hbuf, flags, rankcnt, grpbad, tokp);
}

// Round 6
// 1902.398 us; speedup vs baseline: 1.3600x; 1.3600x over previous
//
#include <hip/hip_runtime.h>
#include <hip/hip_bf16.h>
#include <stdint.h>

#define BDIM 512

constexpr int Bb   = 256;            // batch
constexpr int Tt   = 512;            // timesteps
constexpr int Hh   = 512;            // hidden
constexpr int NPOS = 128, NACT = 64, INPD = 192;
constexpr int GBLK = 16;             // blocks per group (same-XCD, placement-enforced)
constexpr int RR   = 16;             // batch rows per group
constexpr int HHd  = 32;             // h dims per block
constexpr int KITH = Hh / 32;        // 16 h-part MFMA K-iters
constexpr int KITX = INPD / 32;      // 6  x-part MFMA K-iters
constexpr int KIT  = KITH + KITX;    // 22
constexpr int HPAD = Hh + 8;         // 520 shorts per h_s row (1040 B, 16B-aligned)
constexpr int XPAD = INPD + 8;       // 200 shorts per x_s row
constexpr int GPAD = 132;            // gates row stride (fp32)

typedef __attribute__((ext_vector_type(8))) short short8;
typedef __attribute__((ext_vector_type(4))) float f32x4;
typedef __attribute__((ext_vector_type(4))) unsigned int u32x4;

__device__ __forceinline__ float bf2f(unsigned short u) {
  union { unsigned int i; float f; } v; v.i = ((unsigned int)u) << 16; return v.f;
}
__device__ __forceinline__ unsigned short f2bf(float f) {
  __hip_bfloat16 h = __float2bfloat16(f);
  return *reinterpret_cast<unsigned short*>(&h);
}
__device__ __forceinline__ float sigm(float x) { return 1.0f / (1.0f + __expf(-x)); }
__device__ __forceinline__ float tanh_fast(float x) {
  return 1.0f - 2.0f / (1.0f + __expf(2.0f * x));
}

// ---- XCD-local (L2-resident) protocol: plain stores write through the TCP
// into the XCD-shared L2; consumers flash their 32KB L1 (buffer_inv sc0 =
// L1-only, CU-local) then plain-load -> L2 hit. This is LLVM's tgsplit
// workgroup-scope sequence. Verified at runtime per group; fallback below.
__device__ __forceinline__ void l1_inv() {
  asm volatile("buffer_inv sc0" ::: "memory");
  asm volatile("s_waitcnt vmcnt(0)" ::: "memory");
}
// ---- device-scope ops: sc0 sc1 (bypass L1+L2, coherent at IC) — proven r2/r3 ----
__device__ __forceinline__ u32x4 load_dev16(const void* p) {
  u32x4 r;
  asm volatile("global_load_dwordx4 %0, %1, off sc0 sc1" : "=v"(r) : "v"(p) : "memory");
  return r;
}
__device__ __forceinline__ unsigned int load_dev4(const void* p) {
  unsigned int r;
  asm volatile("global_load_dword %0, %1, off sc0 sc1" : "=v"(r) : "v"(p) : "memory");
  return r;
}
__device__ __forceinline__ void store_dev4(void* p, unsigned int v) {
  asm volatile("global_store_dword %0, %1, off sc0 sc1" :: "v"(p), "v"(v) : "memory");
}
__device__ __forceinline__ void store_dev2(void* p, unsigned short v) {
  unsigned int w = v;
  asm volatile("global_store_short %0, %1, off sc0 sc1" :: "v"(p), "v"(w) : "memory");
}
__device__ __forceinline__ void waitvm0() {
  asm volatile("s_waitcnt vmcnt(0)" ::: "memory");
}

__global__ void __launch_bounds__(BDIM, 2)
lstm_kernel(const float* __restrict__ obs, const float* __restrict__ actn,
            const float* __restrict__ h0, const float* __restrict__ c0,
            const float* __restrict__ W_ih, const float* __restrict__ W_hh,
            const float* __restrict__ b_ih, const float* __restrict__ b_hh,
            const float* __restrict__ W_out, const float* __restrict__ b_out,
            float* __restrict__ out, unsigned short* __restrict__ hbuf,
            unsigned int* __restrict__ flags, unsigned int* __restrict__ rankcnt,
            unsigned int* __restrict__ grpbad, unsigned int* __restrict__ tok)
{
  // static LDS ~36.3 KB + 46080 dynamic pad => ~81.3 KB > 80 KB
  // => hard 1 block/CU => bijection blocks<->CUs => exactly 32 blocks/XCD.
  extern __shared__ unsigned char dynpad[];
  __shared__ __align__(16) unsigned short h_s[RR * HPAD]; // [16][520] bf16
  __shared__ __align__(16) unsigned short x_s[RR * XPAD]; // [16][200] bf16: obs|act
  __shared__ float gates_s[RR * GPAD];                    // [16][132] fp32
  __shared__ float c_s[RR * HHd];                         // [16][32] fp32 cell state
  __shared__ float wout_s[Hh];
  __shared__ float bias_s[4 * HHd];
  __shared__ int rank_sh;
  __shared__ int okA_sh, okB_sh, dev_sh;

  const int tid  = threadIdx.x;
  const int wv   = tid >> 6, lane = tid & 63;
  const int cl   = lane & 15, qd = lane >> 4;

  if (rankcnt == nullptr) dynpad[0] = 1;   // keep extern LDS alive (never true)

  // ---- placement-derived grouping (verified below) ----
  unsigned int xcc;
  asm volatile("s_getreg_b32 %0, hwreg(HW_REG_XCC_ID)" : "=s"(xcc));
  xcc &= 7u;
  if (tid == 0)
    rank_sh = (int)__hip_atomic_fetch_add(rankcnt + (size_t)xcc * 32, 1u,
                                          __ATOMIC_RELAXED, __HIP_MEMORY_SCOPE_AGENT);
  __syncthreads();
  const int rank = rank_sh;                            // 0..31 on this XCD
  const int g    = ((int)xcc * 2 + (rank >> 4)) & 15;  // group 0..15 (2 per XCD)
  const int jb   = rank & 15;                          // h-slice 0..15

  unsigned short* hb0 = hbuf;
  unsigned short* hb1 = hbuf + (size_t)Bb * Hh;
  const size_t slotbase = (size_t)(g * GBLK + jb) * (RR * HHd);
  const size_t grpbase  = (size_t)g * GBLK * (RR * HHd);
  unsigned int* myflag = flags + (size_t)(g * GBLK + jb) * 32;     // 128B spacing
  volatile unsigned int* pollflag =
      (volatile unsigned int*)(flags + (size_t)(g * GBLK + (lane & 15)) * 32);
  volatile unsigned int* mytok = (volatile unsigned int*)(tok + (size_t)(g * GBLK + jb) * 32);
  const unsigned int TOKA = 0xA5000000u | (unsigned)(g << 8) | (unsigned)jb;
  const unsigned int TOKB = 0x5A000000u | (unsigned)(g << 8) | (unsigned)jb;

  auto pollv_dev = [&](unsigned int tgt, int valve) {  // device-scope barrier (proven)
    if (tid < 64) {
      int spins = 0;
      for (;;) {
        const unsigned int v = load_dev4((const void*)pollflag);
        waitvm0();
        if (__all((int)(v >= tgt))) break;
        if (++spins > valve) break;
      }
    }
    __syncthreads();
  };
  auto verify_read = [&](unsigned int expbase) {       // FAST protocol reads
    if (tid < 64) {
      int good = 1;
      if (lane < 16) {
        l1_inv();
        const unsigned int v = *(volatile unsigned int*)(tok + (size_t)(g * GBLK + lane) * 32);
        waitvm0();
        good = (v == (expbase | (unsigned)(g << 8) | (unsigned)lane)) ? 1 : 0;
      }
      const int allg = __all(good);
      if (lane == 0) { if (expbase == 0xA5000000u) okA_sh = allg; else okB_sh = allg; }
    }
  };

  // ---- phase 1: token A (FAST plain store) + h0 (device store) ----
  if (tid == 0) *mytok = TOKA;            // plain write-through store
  {
    const int m = tid >> 5, r = tid & 31;
    const size_t gi = (size_t)(g * RR + m) * Hh + jb * HHd + r;
    c_s[tid] = c0[gi];
    store_dev2(hb0 + slotbase + tid, f2bf(h0[gi]));
  }
  waitvm0();
  __syncthreads();
  if (tid == 0) store_dev4(myflag, 1u);
  pollv_dev(1u, 2000000);
  verify_read(0xA5000000u);               // round A: cold-miss path
  __syncthreads();
  if (tid == 0) store_dev4(myflag, 2u);
  pollv_dev(2u, 2000000);
  if (tid == 0) {                         // round B: overwrite same line (stale-L1 detector)
    *mytok = TOKB;
    waitvm0();
    store_dev4(myflag, 3u);
  }
  pollv_dev(3u, 2000000);
  verify_read(0x5A000000u);
  __syncthreads();
  if (tid == 0) {
    if (!(okA_sh && okB_sh)) atomicOr(grpbad + (size_t)g * 32, 1u);
    waitvm0();
    store_dev4(myflag, 4u);
  }
  pollv_dev(4u, 2000000);
  if (tid == 0) {
    const unsigned int gb = load_dev4(grpbad + (size_t)g * 32);
    waitvm0();
    dev_sh = (gb != 0);
  }
  __syncthreads();
  const bool dev = (dev_sh != 0);         // block-uniform scope selector

  // ---- W slice -> register-resident bf16 MFMA B-fragments ----
  short8 wfrag[KIT];
  {
    const int L = wv * 16 + cl, q = L >> 5, r = L & 31;
    const int R = q * Hh + jb * HHd + r;
    const float* whh = W_hh + (size_t)R * Hh;
    const float* wih = W_ih + (size_t)R * INPD;
    #pragma unroll
    for (int kk = 0; kk < KIT; ++kk) {
      const int k0 = kk * 32 + qd * 8;
      short8 s;
      #pragma unroll
      for (int e = 0; e < 8; ++e) {
        const int k = k0 + e;
        const float f = (k < Hh) ? whh[k] : wih[k - Hh];
        s[e] = (short)f2bf(f);
      }
      wfrag[kk] = s;
    }
  }
  if (tid < 128) {
    const int q = tid >> 5, r = tid & 31;
    bias_s[tid] = b_ih[q * Hh + jb * HHd + r] + b_hh[q * Hh + jb * HHd + r];
  }
  wout_s[tid] = W_out[tid];
  const float bout = b_out[0];

  // cooperative coalesced x staging (obs/act fp32 -> bf16 -> x_s)
  auto stage_x = [&](int t) {
    {
      const int m = tid >> 5, c4 = tid & 31;   // 16 rows x 32 float4 = 512 chunks
      const float4 v = *(const float4*)(obs + ((size_t)(g * RR + m) * Tt + t) * NPOS + c4 * 4);
      uint2 p;
      p.x = (unsigned)f2bf(v.x) | ((unsigned)f2bf(v.y) << 16);
      p.y = (unsigned)f2bf(v.z) | ((unsigned)f2bf(v.w) << 16);
      *(uint2*)(&x_s[m * XPAD + c4 * 4]) = p;
    }
    if (tid < 256) {
      const int m = tid >> 4, c4 = tid & 15;   // 16 rows x 16 float4
      const float4 v = *(const float4*)(actn + ((size_t)(g * RR + m) * Tt + t) * NACT + c4 * 4);
      uint2 p;
      p.x = (unsigned)f2bf(v.x) | ((unsigned)f2bf(v.y) << 16);
      p.y = (unsigned)f2bf(v.z) | ((unsigned)f2bf(v.w) << 16);
      *(uint2*)(&x_s[m * XPAD + NPOS + c4 * 4]) = p;
    }
  };
  auto xacc_compute = [&]() -> f32x4 {
    f32x4 a;
    { const float bv = bias_s[wv * 16 + cl]; a = (f32x4){bv, bv, bv, bv}; }
    const unsigned short* xrow = &x_s[cl * XPAD + qd * 8];
    #pragma unroll
    for (int j = 0; j < KITX; ++j)
      a = __builtin_amdgcn_mfma_f32_16x16x32_bf16(*(const short8*)(xrow + j * 32),
                                                  wfrag[KITH + j], a, 0, 0, 0);
    return a;
  };

  stage_x(0);
  __syncthreads();
  f32x4 xacc = xacc_compute();

  for (int t = 0; t < Tt; ++t) {
    const unsigned short* hsrc = (t & 1) ? hb1 : hb0;  // h_{t-1}
    unsigned short* hdst       = (t & 1) ? hb0 : hb1;  // h_t

    // 1. load group's h (16 KB) at the verified scope -> LDS
    u32x4 hv0, hv1;
    if (dev) {
      hv0 = load_dev16(hsrc + grpbase + (size_t)tid * 8);
      hv1 = load_dev16(hsrc + grpbase + (size_t)(tid + 512) * 8);
    } else {
      l1_inv();                                        // L1 flash, then L2 hits
      hv0 = *(const u32x4*)(hsrc + grpbase + (size_t)tid * 8);
      hv1 = *(const u32x4*)(hsrc + grpbase + (size_t)(tid + 512) * 8);
    }
    waitvm0();
    {
      const int i0 = tid, i1 = tid + 512;
      *(u32x4*)&h_s[((i0 & 63) >> 2) * HPAD + ((i0 >> 6) << 5) + ((i0 & 3) << 3)] = hv0;
      *(u32x4*)&h_s[((i1 & 63) >> 2) * HPAD + ((i1 >> 6) << 5) + ((i1 & 3) << 3)] = hv1;
    }
    __syncthreads();                                   // (A) h_s ready

    // 2. h-part MFMA on carried x-part accumulator
    f32x4 acc = xacc;
    const unsigned short* ar = &h_s[cl * HPAD + qd * 8];
    #pragma unroll
    for (int kk = 0; kk < KITH; ++kk)
      acc = __builtin_amdgcn_mfma_f32_16x16x32_bf16(*(const short8*)(ar + kk * 32),
                                                    wfrag[kk], acc, 0, 0, 0);
    #pragma unroll
    for (int rg = 0; rg < 4; ++rg)
      gates_s[(qd * 4 + rg) * GPAD + wv * 16 + cl] = acc[rg];
    __syncthreads();                                   // (B) gates ready

    // 3. LSTM elementwise; h_t published at the verified scope
    {
      const int m = tid >> 5, r = tid & 31;
      const float gi = gates_s[m * GPAD + r];
      const float gf = gates_s[m * GPAD + HHd + r];
      const float gg = gates_s[m * GPAD + 2 * HHd + r];
      const float go = gates_s[m * GPAD + 3 * HHd + r];
      const float cp = c_s[tid];
      const float iv = sigm(gi), fv = sigm(gf);
      const float gv = tanh_fast(gg), ov = sigm(go);
      const float cn = fv * cp + iv * gv;
      const float hn = ov * tanh_fast(cn);
      c_s[tid] = cn;
      const unsigned int hb = (unsigned int)f2bf(hn);
      const unsigned int hb2 = (unsigned int)__shfl_down((int)hb, 1, 64);
      if ((tid & 1) == 0) {
        if (dev) store_dev4(hdst + slotbase + tid, hb | (hb2 << 16));
        else     *(unsigned int*)(hdst + slotbase + tid) = hb | (hb2 << 16);
      }
    }
    waitvm0();          // h stores acked (write-through: in L2 / at IC)
    __syncthreads();    // (C) all waves drained
    if (tid == 0) {
      if (dev) store_dev4(myflag, (unsigned int)(t + 5));
      else     *(volatile unsigned int*)myflag = (unsigned int)(t + 5);
    }

    // 4. barrier window: out[t-1] from h_s, stage+compute x-part for t+1
    if (jb == 0 && t > 0 && tid < 128) {
      const int m = tid >> 3, l8 = tid & 7;
      const unsigned short* hr = &h_s[m * HPAD + l8 * 64];
      const float* wr = &wout_s[l8 * 64];
      float sum = 0.f;
      #pragma unroll 8
      for (int e = 0; e < 64; ++e) sum += bf2f(hr[e]) * wr[e];
      sum += __shfl_down(sum, 4, 64);
      sum += __shfl_down(sum, 2, 64);
      sum += __shfl_down(sum, 1, 64);
      if (l8 == 0) out[(size_t)(g * RR + m) * Tt + (t - 1)] = sum + bout;
    }
    if (t + 1 < Tt) {
      stage_x(t + 1);
      __syncthreads();                                 // (D) x_s ready
      xacc = xacc_compute();
    }

    // 5. all waves poll the group's 16 flags in parallel
    {
      int spins = 0;
      const unsigned int tgt = (unsigned int)(t + 5);
      for (;;) {
        unsigned int v;
        int good = 1;
        if (dev) {
          v = load_dev4((const void*)pollflag);
          waitvm0();
          good = (v >= tgt);
        } else {
          if (lane < 16) {
            l1_inv();
            v = *pollflag;
            waitvm0();
            good = (v >= tgt);
          }
        }
        if (__all(good)) break;
        if (++spins > 50000) break;        // wrong-not-hung safety valve
      }
    }
    __syncthreads();                                   // (E) step boundary
  }

  // final column: h_{T-1} in hb0 (T even), at the verified scope
  if (jb == 0 && tid < 128) {
    const int m = tid >> 3, l8 = tid & 7;
    if (!dev) l1_inv();
    float sum = 0.f;
    #pragma unroll
    for (int it = 0; it < 8; ++it) {
      const int d = l8 * 64 + it * 8;
      const void* p = hb0 + grpbase + (size_t)(d >> 5) * (RR * HHd) + m * HHd + (d & 31);
      const u32x4 v = dev ? load_dev16(p) : *(const u32x4*)p;
      waitvm0();
      #pragma unroll
      for (int j2 = 0; j2 < 4; ++j2) {
        sum += bf2f((unsigned short)(v[j2] & 0xffffu)) * wout_s[d + j2 * 2];
        sum += bf2f((unsigned short)(v[j2] >> 16))     * wout_s[d + j2 * 2 + 1];
      }
    }
    sum += __shfl_down(sum, 4, 64);
    sum += __shfl_down(sum, 2, 64);
    sum += __shfl_down(sum, 1, 64);
    if (l8 == 0) out[(size_t)(g * RR + m) * Tt + (Tt - 1)] = sum + bout;
  }
}

extern "C" void kernel_launch(void* const* d_in, const int* in_sizes, int n_in,
                              void* d_out, int out_size, void* d_ws, size_t ws_size,
                              hipStream_t stream) {
  const float* obs   = (const float*)d_in[0];
  const float* actn  = (const float*)d_in[1];
  const float* h0    = (const float*)d_in[2];
  const float* c0    = (const float*)d_in[3];
  const float* W_ih  = (const float*)d_in[4];
  const float* W_hh  = (const float*)d_in[5];
  const float* b_ih  = (const float*)d_in[6];
  const float* b_hh  = (const float*)d_in[7];
  const float* W_out = (const float*)d_in[8];
  const float* b_out = (const float*)d_in[9];
  float* out = (float*)d_out;

  // ws layout: hbuf 512K | flags 32K | rankcnt 1K | grpbad 2K | tok 32K
  unsigned short* hbuf = (unsigned short*)d_ws;
  char* p = (char*)d_ws + (size_t)2 * Bb * Hh * sizeof(unsigned short);
  unsigned int* flags   = (unsigned int*)p;
  unsigned int* rankcnt = (unsigned int*)(p + 32768);
  unsigned int* grpbad  = (unsigned int*)(p + 32768 + 1024);
  unsigned int* tokp    = (unsigned int*)(p + 32768 + 1024 + 2048);

  hipMemsetAsync(p, 0, 32768 + 1024 + 2048 + 32768, stream);

  // dynamic LDS pad (extern __shared__ referenced in-kernel so it's honored):
  // static ~36.3 KB + 46080 => ~81.3 KB/block -> hard 1 block/CU.
  hipFuncSetAttribute((const void*)lstm_kernel,
                      hipFuncAttributeMaxDynamicSharedMemorySize, 46080);
  hipLaunchKernelGGL(lstm_kernel, dim3(256), dim3(BDIM), 46080, stream,
                     obs, actn, h0, c0, W_ih, W_hh, b_ih, b_hh, W_out, b_out,
                     out, hbuf, flags, rankcnt, grpbad, tokp);
}